// Round 4
// baseline (314.598 us; speedup 1.0000x reference)
//
#include <hip/hip_runtime.h>

constexpr int Dd = 128, Hh = 128, Ww = 128;
constexpr int B_ = 2, L_ = 8;
constexpr int HW = Hh * Ww;
constexpr int S_SP = Dd * HW;            // 2097152
constexpr float CLAMP_MIN = 0.071f;
constexpr float EPS = 1e-5f;

constexpr int HC = 8;                    // output h rows per wave (10-step march)
constexpr int NHC = Hh / HC;             // 16
constexpr int DPB = 4;                   // d planes per block (one per wave)
constexpr int NDQ = Dd / DPB;            // 32
constexpr int NBLK = B_ * NHC * NDQ;     // 1024

// Fused softmax + clamp + 3x3x3 boundary stencil + dice -- barrier-free.
// Each WAVE owns one output d-plane and an 8-row h-chunk, marching h with a
// thread-local rolling vertical sum. The depth 3-sum is formed by loading all
// three input planes (d-1,d,d+1) per row and summing their horizontal 3-sums
// in registers: no LDS sharing, no __syncthreads, waves stream independently.
// 3x redundant softmax (~6 us chip-wide) buys removal of the 2-barriers/step
// load->exp->LDS->sync chain that made the previous version latency-bound.
__global__ __launch_bounds__(256, 2) void fused_kernel(
    const float* __restrict__ pred, const float* __restrict__ tgt,
    float* __restrict__ partial) {
  const int blk = blockIdx.x;
  const int b   = blk >> 9;
  const int rem = blk & 511;
  const int hc  = rem >> 5;                // h-chunk 0..15
  const int dq  = rem & 31;                // d quad  0..31
  const int tid = threadIdx.x;
  const int wl  = tid & 63;
  const int hl  = tid >> 6;                // wave id 0..3
  const int d   = dq * DPB + hl;           // this wave's output plane
  const int h0  = hc * HC;
  const int w0  = wl * 2;
  const int dm = (d == 0) ? 1 : d - 1;         // reflected depth neighbors
  const int dp = (d == Dd - 1) ? Dd - 2 : d + 1;
  const float* Pb = pred + (size_t)b * L_ * S_SP;
  const float* Tb = tgt  + (size_t)b * L_ * S_SP + (size_t)d * HW;
  const float* plane[3] = {Pb + (size_t)dm * HW,
                           Pb + (size_t)d  * HW,
                           Pb + (size_t)dp * HW};

  float ps2[L_][2], s2c[L_][2], cprev[L_][2], rawprev[L_][2];
  float top[L_], bot[L_];
#pragma unroll
  for (int l = 0; l < L_; ++l) {
    top[l] = 0.f; bot[l] = 0.f;
    ps2[l][0] = ps2[l][1] = 0.f;
    s2c[l][0] = s2c[l][1] = 0.f;
    cprev[l][0] = cprev[l][1] = 0.f;
    rawprev[l][0] = rawprev[l][1] = 0.f;
  }

  for (int k = 0; k < HC + 2; ++k) {       // input rows r = h0-1 .. h0+8
    const int r  = h0 - 1 + k;
    const int rr = (r < 0) ? 1 : ((r > Hh - 1) ? Hh - 2 : r);
    const int roff = rr * Ww + w0;

    // issue tgt loads for the emit row first (consumed only at step end)
    float2 tv[L_];
    if (k >= 2) {
      const size_t tbase = (size_t)(r - 1) * Ww + w0;
#pragma unroll
      for (int l = 0; l < L_; ++l)
        tv[l] = *(const float2*)(Tb + (size_t)l * S_SP + tbase);
    }

    // load row rr of all 3 planes x 8 labels
    float2 v[3][L_];
#pragma unroll
    for (int pl = 0; pl < 3; ++pl)
#pragma unroll
      for (int l = 0; l < L_; ++l)
        v[pl][l] = *(const float2*)(plane[pl] + (size_t)l * S_SP + roff);

    // per plane: softmax + clamp + horizontal 3-sum, accumulate depth sum
    float s3d[L_][2];                      // 3x3 (d,w) sum at row rr
    float ctr[L_][2], rawc[L_][2];
#pragma unroll
    for (int l = 0; l < L_; ++l) s3d[l][0] = s3d[l][1] = 0.f;
#pragma unroll
    for (int pl = 0; pl < 3; ++pl) {
      float p0[L_], p1[L_];
      float s0 = 0.f, s1 = 0.f;
#pragma unroll
      for (int l = 0; l < L_; ++l) {
        p0[l] = __expf(v[pl][l].x); s0 += p0[l];   // ~N(0,1): no max-sub
        p1[l] = __expf(v[pl][l].y); s1 += p1[l];
      }
      const float i0 = 1.f / s0, i1 = 1.f / s1;
#pragma unroll
      for (int l = 0; l < L_; ++l) {
        p0[l] = fmaxf(p0[l] * i0, CLAMP_MIN);
        p1[l] = fmaxf(p1[l] * i1, CLAMP_MIN);
      }
#pragma unroll
      for (int l = 0; l < L_; ++l) {
        float lf = __shfl_up(p1[l], 1, 64);
        if (wl == 0) lf = p1[l];               // w=-1 reflects to w=1
        float rf = __shfl_down(p0[l], 1, 64);
        if (wl == 63) rf = p0[l];              // w=128 reflects to w=126
        s3d[l][0] += lf + p0[l] + p1[l];
        s3d[l][1] += p0[l] + p1[l] + rf;
        if (pl == 1) {
          ctr[l][0] = p0[l]; ctr[l][1] = p1[l];
          rawc[l][0] = v[pl][l].x; rawc[l][1] = v[pl][l].y;
        }
      }
    }

    // emit output row o = r-1 (rows o-1,o,o+1 = ps2 + s3d)
    if (k >= 2) {
#pragma unroll
      for (int l = 0; l < L_; ++l) {
        {
          float bt = fabsf(27.f * cprev[l][0] - (ps2[l][0] + s3d[l][0]));
          float bw = 0.5f / (bt + 0.5f);
          top[l] += tv[l].x * rawprev[l][0] * bw;
          bot[l] += (tv[l].x + rawprev[l][0]) * bw;
        }
        {
          float bt = fabsf(27.f * cprev[l][1] - (ps2[l][1] + s3d[l][1]));
          float bw = 0.5f / (bt + 0.5f);
          top[l] += tv[l].y * rawprev[l][1] * bw;
          bot[l] += (tv[l].y + rawprev[l][1]) * bw;
        }
      }
    }

    // rotate rolling state: ps2 <- s2(r-1)+s2(r), s2c <- s2(r)
#pragma unroll
    for (int l = 0; l < L_; ++l) {
      ps2[l][0] = s2c[l][0] + s3d[l][0]; ps2[l][1] = s2c[l][1] + s3d[l][1];
      s2c[l][0] = s3d[l][0];             s2c[l][1] = s3d[l][1];
      cprev[l][0] = ctr[l][0];           cprev[l][1] = ctr[l][1];
      rawprev[l][0] = rawc[l][0];        rawprev[l][1] = rawc[l][1];
    }
  }

  // wave-reduce 16 scalars, then tiny block reduce
#pragma unroll
  for (int l = 0; l < L_; ++l) {
#pragma unroll
    for (int o = 32; o > 0; o >>= 1) {
      top[l] += __shfl_down(top[l], o, 64);
      bot[l] += __shfl_down(bot[l], o, 64);
    }
  }
  __shared__ float red[4][16];
  if (wl == 0) {
#pragma unroll
    for (int l = 0; l < L_; ++l) {
      red[hl][2 * l]     = top[l];
      red[hl][2 * l + 1] = bot[l];
    }
  }
  __syncthreads();
  if (tid < 16) {
    float s = red[0][tid] + red[1][tid] + red[2][tid] + red[3][tid];
    partial[blk * 16 + tid] = s;
  }
}

// 1024 blocks x 16 scalars -> final loss
__global__ void finalize_kernel(const float* __restrict__ partial, float* __restrict__ out) {
  __shared__ float rr[16];
  const int t = threadIdx.x;           // 256 = 16 (b,l) pairs x 16 workers
  const int p = t >> 4;                // b*8 + l
  const int k = t & 15;
  const int b = p >> 3;
  const int l = p & 7;
  float top = 0.f, bot = 0.f;
  for (int m = 0; m < 32; ++m) {       // 512 blocks per b, 32 per worker
    int blk = b * 512 + k * 32 + m;
    top += partial[blk * 16 + 2 * l];
    bot += partial[blk * 16 + 2 * l + 1];
  }
#pragma unroll
  for (int o = 8; o > 0; o >>= 1) {
    top += __shfl_down(top, o, 16);
    bot += __shfl_down(bot, o, 16);
  }
  if (k == 0) rr[p] = 2.f * top / fmaxf(bot, EPS);
  __syncthreads();
  if (t == 0) {
    float s = 0.f;
#pragma unroll
    for (int i = 0; i < 16; ++i) s += rr[i];
    out[0] = -s / 16.f;
  }
}

extern "C" void kernel_launch(void* const* d_in, const int* in_sizes, int n_in,
                              void* d_out, int out_size, void* d_ws, size_t ws_size,
                              hipStream_t stream) {
  const float* pred = (const float*)d_in[0];
  const float* tgt  = (const float*)d_in[1];
  float* partial = (float*)d_ws;                 // 1024*16*4 = 64 KB
  fused_kernel<<<NBLK, 256, 0, stream>>>(pred, tgt, partial);
  finalize_kernel<<<1, 256, 0, stream>>>(partial, (float*)d_out);
}